// Round 3
// baseline (2741.726 us; speedup 1.0000x reference)
//
#include <hip/hip_runtime.h>

// QLlamaAttention on MI355X — round 3: int8-exact GEMM path.
//
// Fake-quant emits dq = q_int * s with q_int in [-127,127] for ALL segments
// (4/6/8-bit) and group=32 along K == v_mfma_i32_16x16x32_i8's K. So every
// qlinear is computed as C[m,n] = sum_g sa[m,g]*sb[n,g]*I_g[m,n] with I_g an
// EXACT i32 MFMA dot (|I| < 2^24 -> i32->f32 cvt exact). This replaces the
// round-1/2 split-bf16 GEMM: 4x less LDS/global staging, 1 MFMA instead of 3,
// better numerics (~1e-6 rel, only fp32 scale-product rounding).
//
// Attention unchanged from round 2 (split-bf16 flash, LDS-staged K/V).

typedef __attribute__((ext_vector_type(8))) short bfrag;   // 8 bf16 = 4 VGPR
typedef __attribute__((ext_vector_type(4))) float ffrag;   // MFMA C/D
typedef __attribute__((ext_vector_type(4))) int v4i;       // i8-MFMA C/D

#define MFMA16(a, b, c) __builtin_amdgcn_mfma_f32_16x16x32_bf16(a, b, c, 0, 0, 0)

__device__ __forceinline__ unsigned short f2bf(float f) {
  unsigned int u = __float_as_uint(f);
  u += 0x7fffu + ((u >> 16) & 1u);            // RNE
  return (unsigned short)(u >> 16);
}
__device__ __forceinline__ float bf2f(unsigned short h) {
  return __uint_as_float(((unsigned int)h) << 16);
}

// ---------------------------------------------------------------- quantize
// One 32-elem group per thread: q_int (i8) + scale (f32). rintf = RNE matches
// jnp.round; true fp32 division matches g/s.
__global__ __launch_bounds__(256) void quant_i8_k(
    const float* __restrict__ src, signed char* __restrict__ q8,
    float* __restrict__ S, int ngroups) {
  int g = blockIdx.x * 256 + threadIdx.x;
  if (g >= ngroups) return;
  int gc = g & 127;                            // group index within a row
  float maxq = (gc < 64) ? 7.f : ((gc < 96) ? 31.f : 127.f);
  const float4* p = (const float4*)(src + (size_t)g * 32);
  float4 v[8];
  float amax = 0.f;
#pragma unroll
  for (int i = 0; i < 8; ++i) {
    v[i] = p[i];
    amax = fmaxf(amax, fmaxf(fmaxf(fabsf(v[i].x), fabsf(v[i].y)),
                             fmaxf(fabsf(v[i].z), fabsf(v[i].w))));
  }
  float s = amax / maxq;
  if (s == 0.f) s = 1.f;
  S[g] = s;                                    // S[row*128 + gc]
  float lc = -maxq - 1.f;
  signed char buf[32];
#pragma unroll
  for (int i = 0; i < 8; ++i) {
    float xs[4] = {v[i].x, v[i].y, v[i].z, v[i].w};
#pragma unroll
    for (int j = 0; j < 4; ++j) {
      float q = rintf(xs[j] / s);
      q = fminf(fmaxf(q, lc), maxq);
      buf[i * 4 + j] = (signed char)(int)q;
    }
  }
  uint4* o = (uint4*)(q8 + (size_t)g * 32);
  o[0] = *(const uint4*)&buf[0];
  o[1] = *(const uint4*)&buf[16];
}

// ---------------------------------------------------------------- RoPE
__global__ __launch_bounds__(256) void rope_split_k(
    const float* __restrict__ src, unsigned short* __restrict__ hi,
    unsigned short* __restrict__ lo) {
  int idx = blockIdx.x * 256 + threadIdx.x;    // [0, 2048*32*64)
  int dp = idx & 63;
  int h = (idx >> 6) & 31;
  int tok = idx >> 11;
  int si = tok & 1023;
  size_t base = (size_t)tok * 4096 + h * 128 + dp;
  float x1 = src[base];
  float x2 = src[base + 64];
  float inv = powf(10000.f, -(float)dp * (1.f / 64.f));
  float ang = (float)si * inv;
  float sn, cs;
  sincosf(ang, &sn, &cs);
  float o1 = x1 * cs - x2 * sn;
  float o2 = x2 * cs + x1 * sn;
  unsigned short h1 = f2bf(o1), h2 = f2bf(o2);
  hi[base] = h1;
  lo[base] = f2bf(o1 - bf2f(h1));
  hi[base + 64] = h2;
  lo[base + 64] = f2bf(o2 - bf2f(h2));
}

// ---------------------------------------------------------------- GEMM (i8)
// C[m,n] = sum_g sa[m,g] sb[n,g] (sum_{k in g} qa qb), NT, K=N=4096 fixed.
// 128x128 tile, BK=128 (4 groups/iter), 4 waves 2x2, wave = 64x64 = 4x4
// 16x16x32-i8 frags. LDS row = 128 B, XOR-swizzled 16B chunks (keeps b64
// frag reads / b128 staging writes at bank-throughput floor). Next tile is
// prefetched into registers during compute. mode 0: fp32 C. mode 1: V
// epilogue -> transposed bf16 hi/lo [(b*32+h)*128+d]*1024+s.
__global__ __launch_bounds__(256, 2) void gemm_i8_k(
    const signed char* __restrict__ Aq, const float* __restrict__ Sa,
    const signed char* __restrict__ Bq, const float* __restrict__ Sb,
    float* __restrict__ Cf, unsigned short* __restrict__ Chi,
    unsigned short* __restrict__ Clo, int mode) {
  __shared__ signed char sA[128 * 128], sB[128 * 128];   // 16 KB each
  __shared__ float sSA[4 * 128], sSB[4 * 128];           // 2 KB each
  int tid = threadIdx.x;
  int w = tid >> 6, lane = tid & 63, quad = lane >> 4, c = lane & 15;
  int wm = w >> 1, wn = w & 1;
  int bm = blockIdx.y * 128, bn = blockIdx.x * 128;
  int trow = tid >> 1, thalf = tid & 1;
  const signed char* Ab = Aq + (size_t)(bm + trow) * 4096 + thalf * 64;
  const signed char* Bb = Bq + (size_t)(bn + trow) * 4096 + thalf * 64;
  const float* Sp = (tid < 128) ? (Sa + (size_t)(bm + tid) * 128)
                                : (Sb + (size_t)(bn + tid - 128) * 128);
  ffrag acc[4][4] = {};
  uint4 ra[4], rb[4];
  float4 rs;
  // prefetch tile 0
  {
    const uint4* pa = (const uint4*)Ab;
    const uint4* pb = (const uint4*)Bb;
#pragma unroll
    for (int i = 0; i < 4; ++i) { ra[i] = pa[i]; rb[i] = pb[i]; }
    rs = *(const float4*)Sp;
  }
  for (int it = 0; it < 32; ++it) {
    __syncthreads();
    {
      int sw = trow & 7;
#pragma unroll
      for (int i = 0; i < 4; ++i) {
        int cc = thalf * 4 + i;
        *(uint4*)&sA[trow * 128 + ((cc ^ sw) << 4)] = ra[i];
        *(uint4*)&sB[trow * 128 + ((cc ^ sw) << 4)] = rb[i];
      }
      if (tid < 128) {
        sSA[tid] = rs.x; sSA[128 + tid] = rs.y;
        sSA[256 + tid] = rs.z; sSA[384 + tid] = rs.w;
      } else {
        int t = tid - 128;
        sSB[t] = rs.x; sSB[128 + t] = rs.y;
        sSB[256 + t] = rs.z; sSB[384 + t] = rs.w;
      }
    }
    __syncthreads();
    if (it + 1 < 32) {                          // prefetch next tile
      int k0 = (it + 1) << 7;
      const uint4* pa = (const uint4*)(Ab + k0);
      const uint4* pb = (const uint4*)(Bb + k0);
#pragma unroll
      for (int i = 0; i < 4; ++i) { ra[i] = pa[i]; rb[i] = pb[i]; }
      rs = *(const float4*)(Sp + (k0 >> 5));
    }
#pragma unroll
    for (int g = 0; g < 4; ++g) {
      int ccq = 2 * g + (quad >> 1);
      int qoff = (quad & 1) << 3;
      long af[4], bf[4];
      float4 sav[4];
      float sbv[4];
#pragma unroll
      for (int i = 0; i < 4; ++i) {
        int row = wm * 64 + i * 16 + c;
        af[i] = *(const long*)&sA[row * 128 + ((ccq ^ (row & 7)) << 4) + qoff];
        sav[i] = *(const float4*)&sSA[g * 128 + wm * 64 + i * 16 + (quad << 2)];
      }
#pragma unroll
      for (int j = 0; j < 4; ++j) {
        int row = wn * 64 + j * 16 + c;
        bf[j] = *(const long*)&sB[row * 128 + ((ccq ^ (row & 7)) << 4) + qoff];
        sbv[j] = sSB[g * 128 + wn * 64 + j * 16 + c];
      }
#pragma unroll
      for (int i = 0; i < 4; ++i)
#pragma unroll
        for (int j = 0; j < 4; ++j) {
          v4i r = __builtin_amdgcn_mfma_i32_16x16x32_i8(af[i], bf[j],
                                                        (v4i){0, 0, 0, 0},
                                                        0, 0, 0);
          float sb0 = sbv[j];
          acc[i][j][0] = fmaf((float)r[0], sav[i].x * sb0, acc[i][j][0]);
          acc[i][j][1] = fmaf((float)r[1], sav[i].y * sb0, acc[i][j][1]);
          acc[i][j][2] = fmaf((float)r[2], sav[i].z * sb0, acc[i][j][2]);
          acc[i][j][3] = fmaf((float)r[3], sav[i].w * sb0, acc[i][j][3]);
        }
    }
  }
#pragma unroll
  for (int i = 0; i < 4; ++i)
#pragma unroll
    for (int j = 0; j < 4; ++j) {
      int m0 = bm + wm * 64 + i * 16 + quad * 4;
      int n = bn + wn * 64 + j * 16 + c;
#pragma unroll
      for (int r = 0; r < 4; ++r) {
        float val = acc[i][j][r];
        if (mode == 1) {
          int tok = m0 + r;
          int bb = tok >> 10, si = tok & 1023;
          int hh = n >> 7, d = n & 127;
          size_t o = ((size_t)(bb * 32 + hh) * 128 + d) * 1024 + si;
          unsigned short hv = f2bf(val);
          Chi[o] = hv;
          Clo[o] = f2bf(val - bf2f(hv));
        } else {
          Cf[(size_t)(m0 + r) * 4096 + n] = val;
        }
      }
    }
}

// ---------------------------------------------------------------- attention
// (unchanged from round 2)
__global__ __launch_bounds__(256, 2) void attn_k(
    const unsigned short* __restrict__ Qh, const unsigned short* __restrict__ Ql,
    const unsigned short* __restrict__ Khg, const unsigned short* __restrict__ Klg,
    const unsigned short* __restrict__ Vhg, const unsigned short* __restrict__ Vlg,
    float* __restrict__ O) {
  __shared__ unsigned short sKh[64 * 128], sKl[64 * 128];   // 16 KB each
  __shared__ unsigned short sVh[128 * 64], sVl[128 * 64];   // 16 KB each
  int qb = blockIdx.x, bh = blockIdx.y;
  int b = bh >> 5, h = bh & 31;
  int tid = threadIdx.x;
  int lane = tid & 63, w = tid >> 6, quad = lane >> 4, c = lane & 15;
  int q0 = qb * 64 + w * 16;
  bfrag bqh[4], bql[4];
  {
    const unsigned short* qr = Qh + ((size_t)(b * 1024 + q0 + c)) * 4096 + h * 128 + quad * 8;
    const unsigned short* qrl = Ql + ((size_t)(b * 1024 + q0 + c)) * 4096 + h * 128 + quad * 8;
#pragma unroll
    for (int kd = 0; kd < 4; ++kd) {
      bqh[kd] = *(const bfrag*)(qr + kd * 32);
      bql[kd] = *(const bfrag*)(qrl + kd * 32);
    }
  }
  int kr = tid >> 4, kc = tid & 15;            // K staging: 16 rows/round
  int vr = tid >> 3, vc = tid & 7;             // V staging: 32 rows/round
  ffrag oacc[8] = {};
  float m_q = -INFINITY, l_q = 0.f;
  const float scale = 0.088388347648318447f;   // 1/sqrt(128)
  const unsigned short* Kb = Khg + ((size_t)b * 1024) * 4096 + h * 128;
  const unsigned short* Klb = Klg + ((size_t)b * 1024) * 4096 + h * 128;
  const unsigned short* Vb = Vhg + ((size_t)bh * 128) * 1024;
  const unsigned short* Vlb = Vlg + ((size_t)bh * 128) * 1024;
  int sA2 = ((quad & 1) << 5) + c;             // P-transpose src lanes
  int sB2 = sA2 + 16;
  for (int kt = 0; kt <= qb; ++kt) {
    __syncthreads();
    {  // ---- stage K tile (64 x 128, hi+lo) ----
      uint4 th[4], tl[4];
#pragma unroll
      for (int rr = 0; rr < 4; ++rr) {
        size_t g = (size_t)(kt * 64 + rr * 16 + kr) * 4096 + kc * 8;
        th[rr] = *(const uint4*)(Kb + g);
        tl[rr] = *(const uint4*)(Klb + g);
      }
#pragma unroll
      for (int rr = 0; rr < 4; ++rr) {
        int row = rr * 16 + kr;
        int off = (row * 16 + (kc ^ (row & 15))) * 8;
        *(uint4*)&sKh[off] = th[rr];
        *(uint4*)&sKl[off] = tl[rr];
      }
    }
    {  // ---- stage Vt tile (128 x 64, hi+lo) ----
      uint4 th[4], tl[4];
#pragma unroll
      for (int rr = 0; rr < 4; ++rr) {
        size_t g = (size_t)(rr * 32 + vr) * 1024 + kt * 64 + vc * 8;
        th[rr] = *(const uint4*)(Vb + g);
        tl[rr] = *(const uint4*)(Vlb + g);
      }
#pragma unroll
      for (int rr = 0; rr < 4; ++rr) {
        int row = rr * 32 + vr;
        int off = (row * 8 + (vc ^ (row & 7))) * 8;
        *(uint4*)&sVh[off] = th[rr];
        *(uint4*)&sVl[off] = tl[rr];
      }
    }
    __syncthreads();
    // ---- S = K Q^T ----
    ffrag sf[4] = {};
#pragma unroll
    for (int kd = 0; kd < 4; ++kd) {
      bfrag ah[4], al[4];
#pragma unroll
      for (int kb = 0; kb < 4; ++kb) {
        int off = ((kb * 16 + c) * 16 + ((kd * 4 + quad) ^ c)) * 8;
        ah[kb] = *(const bfrag*)&sKh[off];
        al[kb] = *(const bfrag*)&sKl[off];
      }
#pragma unroll
      for (int kb = 0; kb < 4; ++kb) {
        sf[kb] = MFMA16(ah[kb], bqh[kd], sf[kb]);
        sf[kb] = MFMA16(ah[kb], bql[kd], sf[kb]);
        sf[kb] = MFMA16(al[kb], bqh[kd], sf[kb]);
      }
    }
    float rmax = -INFINITY;
    bool diag = (kt == qb);
#pragma unroll
    for (int kb = 0; kb < 4; ++kb)
#pragma unroll
      for (int r = 0; r < 4; ++r) {
        float v = sf[kb][r] * scale;
        if (diag && (kb * 16 + quad * 4 + r) > (w * 16 + c)) v = -1e30f;
        sf[kb][r] = v;
        rmax = fmaxf(rmax, v);
      }
    rmax = fmaxf(rmax, __shfl_xor(rmax, 16, 64));
    rmax = fmaxf(rmax, __shfl_xor(rmax, 32, 64));
    float mn = fmaxf(m_q, rmax);
    float alpha = __expf(m_q - mn);
    m_q = mn;
    bfrag ph[2], pl[2];
    float rsum = 0.f;
#pragma unroll
    for (int sblk = 0; sblk < 2; ++sblk)
#pragma unroll
      for (int j = 0; j < 8; ++j) {
        int srclane = (j < 4) ? sA2 : sB2;
        float v0 = __shfl(sf[sblk * 2 + 0][j & 3], srclane, 64);
        float v1 = __shfl(sf[sblk * 2 + 1][j & 3], srclane, 64);
        float v = (quad < 2) ? v0 : v1;
        float p = __expf(v - m_q);
        rsum += p;
        unsigned short hp = f2bf(p);
        ph[sblk][j] = (short)hp;
        pl[sblk][j] = (short)f2bf(p - bf2f(hp));
      }
    rsum += __shfl_xor(rsum, 16, 64);
    rsum += __shfl_xor(rsum, 32, 64);
    l_q = l_q * alpha + rsum;
    float al4[4];
#pragma unroll
    for (int r = 0; r < 4; ++r) al4[r] = __shfl(alpha, quad * 4 + r, 64);
#pragma unroll
    for (int db = 0; db < 8; ++db)
#pragma unroll
      for (int r = 0; r < 4; ++r) oacc[db][r] *= al4[r];
#pragma unroll
    for (int db = 0; db < 8; ++db) {
#pragma unroll
      for (int sblk = 0; sblk < 2; ++sblk) {
        int off = ((db * 16 + c) * 8 + ((sblk * 4 + quad) ^ (c & 7))) * 8;
        bfrag vh_ = *(const bfrag*)&sVh[off];
        bfrag vl_ = *(const bfrag*)&sVl[off];
        oacc[db] = MFMA16(ph[sblk], vh_, oacc[db]);
        oacc[db] = MFMA16(ph[sblk], vl_, oacc[db]);
        oacc[db] = MFMA16(pl[sblk], vh_, oacc[db]);
      }
    }
  }
  float invl[4];
#pragma unroll
  for (int r = 0; r < 4; ++r) invl[r] = 1.f / __shfl(l_q, quad * 4 + r, 64);
#pragma unroll
  for (int db = 0; db < 8; ++db)
#pragma unroll
    for (int r = 0; r < 4; ++r)
      O[((size_t)(b * 1024 + q0 + quad * 4 + r)) * 4096 + h * 128 + db * 16 + c] =
          oacc[db][r] * invl[r];
}

// ---------------------------------------------------------------- launcher
extern "C" void kernel_launch(void* const* d_in, const int* in_sizes, int n_in,
                              void* d_out, int out_size, void* d_ws, size_t ws_size,
                              hipStream_t stream) {
  (void)in_sizes; (void)n_in; (void)out_size; (void)ws_size;
  const float* x = (const float*)d_in[0];
  const float* Wq = (const float*)d_in[1];
  const float* Wk = (const float*)d_in[2];
  const float* Wv = (const float*)d_in[3];
  const float* Wo = (const float*)d_in[4];
  float* out = (float*)d_out;
  char* ws = (char*)d_ws;
  const size_t MB = 1024ull * 1024ull;
  signed char* Xq = (signed char*)(ws);                    // 8 MB (2048x4096 i8)
  float* SxA = (float*)(ws + 8 * MB);                      // 1 MB scales
  signed char* Wqb = (signed char*)(ws + 16 * MB);         // 16 MB (4096x4096 i8)
  float* SW = (float*)(ws + 32 * MB);                      // 2 MB scales
  float* S1 = (float*)(ws + 64 * MB);                      // 32 MB fp32
  unsigned short* Qh = (unsigned short*)(ws + 96 * MB);
  unsigned short* Ql = (unsigned short*)(ws + 112 * MB);
  unsigned short* Kh = (unsigned short*)(ws + 128 * MB);
  unsigned short* Kl = (unsigned short*)(ws + 144 * MB);
  unsigned short* Vh = (unsigned short*)(ws + 160 * MB);   // transposed [b,h,d,s]
  unsigned short* Vl = (unsigned short*)(ws + 176 * MB);

  dim3 gg(32, 16), gb(256);
  quant_i8_k<<<1024, 256, 0, stream>>>(x, Xq, SxA, 2048 * 128);
  quant_i8_k<<<2048, 256, 0, stream>>>(Wq, Wqb, SW, 4096 * 128);
  gemm_i8_k<<<gg, gb, 0, stream>>>(Xq, SxA, Wqb, SW, S1, nullptr, nullptr, 0);
  rope_split_k<<<16384, 256, 0, stream>>>(S1, Qh, Ql);
  quant_i8_k<<<2048, 256, 0, stream>>>(Wk, Wqb, SW, 4096 * 128);
  gemm_i8_k<<<gg, gb, 0, stream>>>(Xq, SxA, Wqb, SW, S1, nullptr, nullptr, 0);
  rope_split_k<<<16384, 256, 0, stream>>>(S1, Kh, Kl);
  quant_i8_k<<<2048, 256, 0, stream>>>(Wv, Wqb, SW, 4096 * 128);
  gemm_i8_k<<<gg, gb, 0, stream>>>(Xq, SxA, Wqb, SW, nullptr, Vh, Vl, 1);
  attn_k<<<dim3(16, 64), 256, 0, stream>>>(Qh, Ql, Kh, Kl, Vh, Vl, S1);
  quant_i8_k<<<1024, 256, 0, stream>>>(S1, Xq, SxA, 2048 * 128);
  quant_i8_k<<<2048, 256, 0, stream>>>(Wo, Wqb, SW, 4096 * 128);
  gemm_i8_k<<<gg, gb, 0, stream>>>(Xq, SxA, Wqb, SW, out, nullptr, nullptr, 0);
}